// Round 10
// baseline (139.706 us; speedup 1.0000x reference)
//
#include <hip/hip_runtime.h>

// out[n,o,j,i] = sum_{a,b} inp[n,2,i+a,j+b] * kt[o,a,b]
//   inp: (32,3,224,224) f32, kt: (64,5,5) f32, out: (32,64,220,220) f32
//
// R9: R4 (85.8us) with ONE change: 8 blocks/CU instead of 4
// (__launch_bounds__(256,8)). R8 proved nt >> regular (85.8 vs 126.5).
// Issue arithmetic says only ~36us of the 86 is instruction issue ->
// testing whether the residual is overlap (staging phases with no stores
// in flight + shallow block pool). 64 nt-streams/CU sits between R4's
// safe 32 and R5's toxic 128.

#define IMG    224
#define OHW    220
#define FLAT   (OHW * OHW)     // 48400
#define NOUT   64
#define KW     5
#define BLOCK  256
#define QPB    (BLOCK * 4)     // outputs per (block, channel) = 1024
#define NBX    48              // ceil(48400 / 1024)
#define OG     8               // channels per block
#define COLS   10              // staged input columns (<=6 output cols + 4 halo)
#define PR     228             // transposed slab pitch (words), %4==0 for b128
#define SLAB   (COLS * PR)     // 2280 floats = 9120 B

typedef float floatx4 __attribute__((ext_vector_type(4)));

__global__ __launch_bounds__(BLOCK, 8)
void ConvolutionalLayer_88742614270062_kernel(const float* __restrict__ inp,
                                              const float* __restrict__ kt,
                                              float* __restrict__ out) {
    __shared__ float s[SLAB];   // s[c*PR + r]: transposed slab

    const int n   = blockIdx.z;
    const int og  = blockIdx.y * OG;        // first channel of this block
    const int f0  = blockIdx.x * QPB;       // first flat output index
    const int jlo = f0 / OHW;               // first output column touched

    const float* __restrict__ xb = inp + ((size_t)(n * 3 + 2)) * (IMG * IMG);

    // Stage once per block: 224 rows x 10 cols, transposed, right edge guarded.
    for (int idx = threadIdx.x; idx < IMG * COLS; idx += BLOCK) {
        int r   = idx / COLS;
        int c   = idx - r * COLS;
        int col = jlo + c;
        s[c * PR + r] = (col < IMG) ? xb[r * IMG + col] : 0.0f;
    }
    __syncthreads();

    const int  f    = f0 + (int)threadIdx.x * 4;
    const bool live = (f < FLAT);
    const int  fc   = live ? f : (FLAT - 4);    // clamp for safe LDS reads
    const int  j    = fc / OHW;
    const int  i4   = fc - j * OHW;             // multiple of 4
    const int  cj   = j - jlo;                  // 0..5

    // 5 cols x 8 rows window: two aligned conflict-free ds_read_b128 per col.
    float w8[KW][8];
#pragma unroll
    for (int b = 0; b < KW; ++b) {
        const floatx4* p = reinterpret_cast<const floatx4*>(&s[(cj + b) * PR + i4]);
        floatx4 lo = p[0];
        floatx4 hi = p[1];
        w8[b][0] = lo.x; w8[b][1] = lo.y; w8[b][2] = lo.z; w8[b][3] = lo.w;
        w8[b][4] = hi.x; w8[b][5] = hi.y; w8[b][6] = hi.z; w8[b][7] = hi.w;
    }

    // Weights: og wave-uniform -> scalar loads from kt.
    const float* __restrict__ wk = kt + og * (KW * KW);
    float* __restrict__ op = out + ((size_t)(n * NOUT + og)) * FLAT + f;

#pragma unroll
    for (int oc = 0; oc < OG; ++oc) {
        float a0 = 0.f, a1 = 0.f, a2 = 0.f, a3 = 0.f;
#pragma unroll
        for (int a = 0; a < KW; ++a) {
#pragma unroll
            for (int b = 0; b < KW; ++b) {
                float w = wk[oc * (KW * KW) + a * KW + b];
                a0 = fmaf(w, w8[b][a    ], a0);
                a1 = fmaf(w, w8[b][a + 1], a1);
                a2 = fmaf(w, w8[b][a + 2], a2);
                a3 = fmaf(w, w8[b][a + 3], a3);
            }
        }
        if (live) {
            floatx4 v = { a0, a1, a2, a3 };
            __builtin_nontemporal_store(v,
                reinterpret_cast<floatx4*>(op + (size_t)oc * FLAT));
        }
    }
}

extern "C" void kernel_launch(void* const* d_in, const int* in_sizes, int n_in,
                              void* d_out, int out_size, void* d_ws, size_t ws_size,
                              hipStream_t stream) {
    const float* inp = (const float*)d_in[0];   // (32,3,224,224)
    const float* kt  = (const float*)d_in[1];   // (64,5,5)
    float* out       = (float*)d_out;           // (32,64,220,220)

    dim3 grid(NBX, NOUT / OG, 32);              // 48 x 8 x 32 blocks
    ConvolutionalLayer_88742614270062_kernel<<<grid, BLOCK, 0, stream>>>(inp, kt, out);
}

// Round 11
// 90.476 us; speedup vs baseline: 1.5441x; 1.5441x over previous
//
#include <hip/hip_runtime.h>

// out[n,o,j,i] = sum_{a,b} inp[n,2,i+a,j+b] * kt[o,a,b]
//   inp: (32,3,224,224) f32, kt: (64,5,5) f32, out: (32,64,220,220) f32
//
// R10: R4's exact stream structure (4 blocks/CU, OG=8, nt stores = the
// proven 32 streams/CU sweet spot) but QPT=4 quads per thread:
//   - per-channel contiguous run per block: 4KB -> 16KB
//   - blocks: 12288 -> 3072 (setup amortized 4x)
//   - staging redundancy: 0.27 -> 0.16 words/output
//   - window ds_reads and FMAs: device-total UNCHANGED
// Streams/CU unchanged -> no R5/R9-style RMW risk.

#define IMG    224
#define OHW    220
#define FLAT   (OHW * OHW)     // 48400
#define NOUT   64
#define KW     5
#define BLOCK  256
#define QPT    4               // quads per thread
#define OPB    (BLOCK * 4 * QPT)  // 4096 outputs per (block, channel)
#define NBX    12              // ceil(48400 / 4096)
#define OG     8               // channels per block
#define COLS   24              // 19 output cols + 4 halo + 1
#define PR     228             // transposed slab pitch (words), %4==0 for b128
#define SLAB   (COLS * PR)     // 5472 words = 21,888 B

typedef float floatx4 __attribute__((ext_vector_type(4)));

__global__ __launch_bounds__(BLOCK, 4)
void ConvolutionalLayer_88742614270062_kernel(const float* __restrict__ inp,
                                              const float* __restrict__ kt,
                                              float* __restrict__ out) {
    __shared__ float s[SLAB];   // s[c*PR + r]: transposed slab

    const int n   = blockIdx.z;
    const int og  = blockIdx.y * OG;        // first channel of this block
    const int f0  = blockIdx.x * OPB;       // first flat output index
    const int jlo = f0 / OHW;               // first output column touched

    const float* __restrict__ xb = inp + ((size_t)(n * 3 + 2)) * (IMG * IMG);

    // Stage once per block: 224 rows x 24 cols, transposed, right edge guarded.
    for (int idx = threadIdx.x; idx < IMG * COLS; idx += BLOCK) {
        int r   = idx / COLS;
        int c   = idx - r * COLS;
        int col = jlo + c;
        s[c * PR + r] = (col < IMG) ? xb[r * IMG + col] : 0.0f;
    }
    __syncthreads();

    const float* __restrict__ wk = kt + og * (KW * KW);   // wave-uniform
    float* __restrict__ base = out + ((size_t)(n * NOUT + og)) * FLAT;

#pragma unroll 1
    for (int it = 0; it < QPT; ++it) {
        const int  f    = f0 + (it << 10) + ((int)threadIdx.x << 2);
        const bool live = (f < FLAT);
        const int  fc   = live ? f : (FLAT - 4);   // clamp for safe LDS reads
        const int  j    = fc / OHW;
        const int  i4   = fc - j * OHW;            // multiple of 4
        const int  cj   = j - jlo;                 // 0..19

        // 5 cols x 8 rows window: two aligned conflict-free ds_read_b128/col.
        float w8[KW][8];
#pragma unroll
        for (int b = 0; b < KW; ++b) {
            const floatx4* p =
                reinterpret_cast<const floatx4*>(&s[(cj + b) * PR + i4]);
            floatx4 lo = p[0];
            floatx4 hi = p[1];
            w8[b][0] = lo.x; w8[b][1] = lo.y; w8[b][2] = lo.z; w8[b][3] = lo.w;
            w8[b][4] = hi.x; w8[b][5] = hi.y; w8[b][6] = hi.z; w8[b][7] = hi.w;
        }

#pragma unroll
        for (int oc = 0; oc < OG; ++oc) {
            float a0 = 0.f, a1 = 0.f, a2 = 0.f, a3 = 0.f;
#pragma unroll
            for (int a = 0; a < KW; ++a) {
#pragma unroll
                for (int b = 0; b < KW; ++b) {
                    float w = wk[oc * (KW * KW) + a * KW + b];
                    a0 = fmaf(w, w8[b][a    ], a0);
                    a1 = fmaf(w, w8[b][a + 1], a1);
                    a2 = fmaf(w, w8[b][a + 2], a2);
                    a3 = fmaf(w, w8[b][a + 3], a3);
                }
            }
            if (live) {
                floatx4 v = { a0, a1, a2, a3 };
                __builtin_nontemporal_store(v,
                    reinterpret_cast<floatx4*>(base + (size_t)oc * FLAT + f));
            }
        }
    }
}

extern "C" void kernel_launch(void* const* d_in, const int* in_sizes, int n_in,
                              void* d_out, int out_size, void* d_ws, size_t ws_size,
                              hipStream_t stream) {
    const float* inp = (const float*)d_in[0];   // (32,3,224,224)
    const float* kt  = (const float*)d_in[1];   // (64,5,5)
    float* out       = (float*)d_out;           // (32,64,220,220)

    dim3 grid(NBX, NOUT / OG, 32);              // 12 x 8 x 32 blocks
    ConvolutionalLayer_88742614270062_kernel<<<grid, BLOCK, 0, stream>>>(inp, kt, out);
}

// Round 12
// 88.676 us; speedup vs baseline: 1.5755x; 1.0203x over previous
//
#include <hip/hip_runtime.h>

// out[n,o,j,i] = sum_{a,b} inp[n,2,i+a,j+b] * kt[o,a,b]
//   inp: (32,3,224,224) f32, kt: (64,5,5) f32, out: (32,64,220,220) f32
//
// R11: exact R4 (85.8us anchor) with ONE change: stores issued via inline
// asm "global_store_dwordx4 ... sc0 sc1 nt" (system-scope streaming) so
// writes go PAST the per-XCD L2. Theory: nt's 4.6 TB/s cap is L2
// dirty-line eviction ordering (hash/completion order, 128B granules);
// scope-forced write-through delivers each wave's 1KB aligned burst to
// the controller in issue order. Each wave store = 8 complete 128B lines.

#define IMG    224
#define OHW    220
#define FLAT   (OHW * OHW)     // 48400
#define NOUT   64
#define KW     5
#define BLOCK  256
#define QPB    (BLOCK * 4)     // outputs per (block, channel) = 1024
#define NBX    48              // ceil(48400 / 1024)
#define OG     8               // channels per block
#define COLS   10              // staged input columns (<=6 output cols + 4 halo)
#define PR     228             // transposed slab pitch (words), %4==0 for b128
#define SLAB   (COLS * PR)     // 2280 floats = 9120 B

typedef float floatx4 __attribute__((ext_vector_type(4)));

__global__ __launch_bounds__(BLOCK, 4)
void ConvolutionalLayer_88742614270062_kernel(const float* __restrict__ inp,
                                              const float* __restrict__ kt,
                                              float* __restrict__ out) {
    __shared__ float s[SLAB];   // s[c*PR + r]: transposed slab

    const int n   = blockIdx.z;
    const int og  = blockIdx.y * OG;        // first channel of this block
    const int f0  = blockIdx.x * QPB;       // first flat output index
    const int jlo = f0 / OHW;               // first output column touched

    const float* __restrict__ xb = inp + ((size_t)(n * 3 + 2)) * (IMG * IMG);

    // Stage once per block: 224 rows x 10 cols, transposed, right edge guarded.
    for (int idx = threadIdx.x; idx < IMG * COLS; idx += BLOCK) {
        int r   = idx / COLS;
        int c   = idx - r * COLS;
        int col = jlo + c;
        s[c * PR + r] = (col < IMG) ? xb[r * IMG + col] : 0.0f;
    }
    __syncthreads();

    const int  f    = f0 + (int)threadIdx.x * 4;
    const bool live = (f < FLAT);
    const int  fc   = live ? f : (FLAT - 4);    // clamp for safe LDS reads
    const int  j    = fc / OHW;
    const int  i4   = fc - j * OHW;             // multiple of 4
    const int  cj   = j - jlo;                  // 0..5

    // 5 cols x 8 rows window: two aligned conflict-free ds_read_b128 per col.
    float w8[KW][8];
#pragma unroll
    for (int b = 0; b < KW; ++b) {
        const floatx4* p = reinterpret_cast<const floatx4*>(&s[(cj + b) * PR + i4]);
        floatx4 lo = p[0];
        floatx4 hi = p[1];
        w8[b][0] = lo.x; w8[b][1] = lo.y; w8[b][2] = lo.z; w8[b][3] = lo.w;
        w8[b][4] = hi.x; w8[b][5] = hi.y; w8[b][6] = hi.z; w8[b][7] = hi.w;
    }

    // Weights: og wave-uniform -> scalar loads from kt.
    const float* __restrict__ wk = kt + og * (KW * KW);
    float* __restrict__ op = out + ((size_t)(n * NOUT + og)) * FLAT + f;

#pragma unroll
    for (int oc = 0; oc < OG; ++oc) {
        float a0 = 0.f, a1 = 0.f, a2 = 0.f, a3 = 0.f;
#pragma unroll
        for (int a = 0; a < KW; ++a) {
#pragma unroll
            for (int b = 0; b < KW; ++b) {
                float w = wk[oc * (KW * KW) + a * KW + b];
                a0 = fmaf(w, w8[b][a    ], a0);
                a1 = fmaf(w, w8[b][a + 1], a1);
                a2 = fmaf(w, w8[b][a + 2], a2);
                a3 = fmaf(w, w8[b][a + 3], a3);
            }
        }
        if (live) {
            floatx4 v = { a0, a1, a2, a3 };
            float* dst = op + (size_t)oc * FLAT;
            // system-scope streaming store: bypass per-XCD L2 reordering.
            // No "memory" clobber: nothing in-kernel reads d_out, and we
            // don't want the weight regs invalidated across iterations.
            asm volatile("global_store_dwordx4 %0, %1, off sc0 sc1 nt"
                         :: "v"(dst), "v"(v));
        }
    }
}

extern "C" void kernel_launch(void* const* d_in, const int* in_sizes, int n_in,
                              void* d_out, int out_size, void* d_ws, size_t ws_size,
                              hipStream_t stream) {
    const float* inp = (const float*)d_in[0];   // (32,3,224,224)
    const float* kt  = (const float*)d_in[1];   // (64,5,5)
    float* out       = (float*)d_out;           // (32,64,220,220)

    dim3 grid(NBX, NOUT / OG, 32);              // 48 x 8 x 32 blocks
    ConvolutionalLayer_88742614270062_kernel<<<grid, BLOCK, 0, stream>>>(inp, kt, out);
}